// Round 1
// baseline (325.337 us; speedup 1.0000x reference)
//
#include <hip/hip_runtime.h>
#include <cmath>

#define NB   2048
#define ND   512
#define NL   8
#define NLAB 128
#define MAXM 64
#define TOPK_ 5
#define NTH  256
#define MAXSLOT 9   // ceil(64*65/2 / 256)

// ---------------------------------------------------------------------------
// Per-label Gram: G[i][j] = clip(cos(x_i, x_j)) for the m group members.
// Raw dots accumulated from LDS (k-major, stride 67 => conflict-free-ish),
// diag gives norms; normalize+clip in place. Ends with __syncthreads().
// ---------------------------------------------------------------------------
__device__ __forceinline__ void gram_compute(
    const float* __restrict__ X,          // layer base (2048 x 512)
    const int* g, int m, int tid,
    float (*Xt)[67], float (*Gs)[65], float* rinv)
{
    const int P = m * (m + 1) / 2;
    float acc0[MAXSLOT], acc1[MAXSLOT];
    short is_[MAXSLOT], js_[MAXSLOT];
    int ns = 0;
    for (int p = tid; p < P; p += NTH) {
        int i = (int)((sqrtf(8.0f * (float)p + 1.0f) - 1.0f) * 0.5f);
        while (((i + 1) * (i + 2)) / 2 <= p) ++i;
        while ((i * (i + 1)) / 2 > p) --i;
        is_[ns] = (short)i;
        js_[ns] = (short)(p - (i * (i + 1)) / 2);
        acc0[ns] = 0.0f; acc1[ns] = 0.0f;
        ++ns;
    }
    for (int kc = 0; kc < ND; kc += 128) {
        __syncthreads();   // protect Xt reuse from previous chunk / previous call
        for (int idx = tid; idx < (m << 7); idx += NTH) {
            int i = idx >> 7, k = idx & 127;
            Xt[k][i] = X[(g[i] << 9) + kc + k];
        }
        __syncthreads();
        for (int s = 0; s < ns; ++s) {
            int i = is_[s], j = js_[s];
            float a0 = acc0[s], a1 = acc1[s];
            #pragma unroll 8
            for (int k = 0; k < 128; k += 2) {
                a0 = fmaf(Xt[k][i],     Xt[k][j],     a0);
                a1 = fmaf(Xt[k + 1][i], Xt[k + 1][j], a1);
            }
            acc0[s] = a0; acc1[s] = a1;
        }
    }
    __syncthreads();
    for (int s = 0; s < ns; ++s) {
        int i = is_[s], j = js_[s];
        float v = acc0[s] + acc1[s];
        Gs[i][j] = v; Gs[j][i] = v;
    }
    __syncthreads();
    if (tid < m) rinv[tid] = 1.0f / fmaxf(sqrtf(Gs[tid][tid]), 1e-8f);
    __syncthreads();
    for (int idx = tid; idx < (m << 6); idx += NTH) {
        int i = idx >> 6, j = idx & 63;
        if (j < m) {
            float v = Gs[i][j] * rinv[i] * rinv[j];
            v = fminf(fmaxf(v, -1.0f), 1.0f);   // jax f32 clip(-1+1e-8, 1-1e-8) == +-1.0f
            Gs[i][j] = v;
        }
    }
    __syncthreads();
}

// ---------------------------------------------------------------------------
// Bucket labels -> ordered member lists (index-ascending, deterministic).
// Also zeroes the pair accumulators (ws is re-poisoned before every call).
// ---------------------------------------------------------------------------
__global__ __launch_bounds__(NTH) void k_bucket(
    const int* __restrict__ labels, int* __restrict__ members,
    int* __restrict__ cnt, float* accn, float* accd, float* accc)
{
    __shared__ int cnts[NTH];
    int c = blockIdx.x, tid = threadIdx.x;
    int my[8]; int n = 0;
    int base_i = tid * 8;
    for (int t = 0; t < 8; ++t) {
        int i = base_i + t;
        if (labels[i] == c) my[n++] = i;
    }
    cnts[tid] = n;
    __syncthreads();
    for (int off = 1; off < NTH; off <<= 1) {
        int v = (tid >= off) ? cnts[tid - off] : 0;
        __syncthreads();
        cnts[tid] += v;
        __syncthreads();
    }
    int excl = cnts[tid] - n;
    if (tid == 0) cnt[c] = cnts[NTH - 1];
    for (int t = 0; t < n; ++t) {
        int slot = excl + t;
        if (slot < MAXM) members[c * MAXM + slot] = my[t];
    }
    if (c == 0 && tid < NL - 1) { accn[tid] = 0.f; accd[tid] = 0.f; accc[tid] = 0.f; }
}

// ---------------------------------------------------------------------------
// Phase 1: layer-7 full-group knn -> in_sub bitmask per label
// ---------------------------------------------------------------------------
__global__ __launch_bounds__(NTH) void k_phase1(
    const float* __restrict__ feats, const int* __restrict__ members,
    const int* __restrict__ cnt, unsigned long long* __restrict__ insub)
{
    __shared__ float Xt[128][67];
    __shared__ float Gs[64][65];
    __shared__ float rinv[64];
    __shared__ unsigned long long tops_s[64];
    __shared__ unsigned char keep_s[64];
    __shared__ int g_s[64];
    int c = blockIdx.x, tid = threadIdx.x;
    int m = cnt[c]; if (m > MAXM) m = MAXM;
    if (m == 0) { if (tid == 0) insub[c] = 0ull; return; }
    if (tid < m) g_s[tid] = members[c * MAXM + tid];
    __syncthreads();
    gram_compute(feats + (size_t)7 * NB * ND, g_s, m, tid, Xt, Gs, rinv);

    unsigned long long tops = 0ull; bool keep = false;
    if (tid < m) {
        int cand = 0;
        for (int j = 0; j < m; ++j)
            if (j != tid && Gs[tid][j] > 0.0f) ++cand;
        keep = (cand >= TOPK_);
        if (keep) {
            for (int r = 0; r < TOPK_; ++r) {
                float bv = 0.0f; int bj = -1;
                for (int j = 0; j < m; ++j) {
                    if (j == tid || ((tops >> j) & 1ull)) continue;
                    float v = Gs[tid][j];
                    if (v > 0.0f && v > bv) { bv = v; bj = j; }  // ties -> lowest index
                }
                if (bj >= 0) tops |= (1ull << bj);
            }
        }
        keep_s[tid] = keep ? 1 : 0; tops_s[tid] = tops;
    }
    __syncthreads();
    unsigned long long Mrow = 0ull;
    if (tid < m && keep) {
        for (int j = 0; j < m; ++j) {
            if (j == tid || !keep_s[j]) continue;
            if (((tops >> j) & 1ull) || ((tops_s[j] >> tid) & 1ull)) Mrow |= (1ull << j);
        }
    }
    if (tid < 64) {
        unsigned long long b = __ballot(Mrow != 0ull);
        if (tid == 0) insub[c] = b;
    }
}

// ---------------------------------------------------------------------------
// Per (label, layer): Gram + subset-restricted knn -> M bitmask + ema
// ---------------------------------------------------------------------------
__global__ __launch_bounds__(NTH) void k_decide(
    const float* __restrict__ feats, const int* __restrict__ members,
    const int* __restrict__ cnt, const unsigned long long* __restrict__ insub,
    unsigned long long* __restrict__ Mbits, float* __restrict__ ema)
{
    __shared__ float Xt[128][67];
    __shared__ float Gs[64][65];
    __shared__ float rinv[64];
    __shared__ unsigned long long tops_s[64];
    __shared__ unsigned char keep_s[64];
    __shared__ int g_s[64];
    int c = blockIdx.x, l = blockIdx.y, tid = threadIdx.x;
    int m = cnt[c]; if (m > MAXM) m = MAXM;
    if (m == 0) return;
    unsigned long long sub = insub[c];
    if (tid < m) g_s[tid] = members[c * MAXM + tid];
    __syncthreads();
    gram_compute(feats + (size_t)l * NB * ND, g_s, m, tid, Xt, Gs, rinv);

    unsigned long long tops = 0ull; bool keep = false; bool act = false;
    if (tid < m) {
        act = (sub >> tid) & 1ull;
        int cand = 0;
        if (act) {
            for (int j = 0; j < m; ++j)
                if (j != tid && ((sub >> j) & 1ull) && Gs[tid][j] > 0.0f) ++cand;
        }
        keep = act && (cand >= TOPK_);
        if (keep) {
            for (int r = 0; r < TOPK_; ++r) {
                float bv = 0.0f; int bj = -1;
                for (int j = 0; j < m; ++j) {
                    if (j == tid || !((sub >> j) & 1ull) || ((tops >> j) & 1ull)) continue;
                    float v = Gs[tid][j];
                    if (v > 0.0f && v > bv) { bv = v; bj = j; }
                }
                if (bj >= 0) tops |= (1ull << bj);
            }
        }
        keep_s[tid] = keep ? 1 : 0; tops_s[tid] = tops;
    }
    __syncthreads();
    if (tid < m) {
        unsigned long long Mrow = 0ull;
        if (keep) {
            for (int j = 0; j < m; ++j) {
                if (j == tid || !keep_s[j]) continue;
                if (((tops >> j) & 1ull) || ((tops_s[j] >> tid) & 1ull)) Mrow |= (1ull << j);
            }
        }
        Mbits[((size_t)l * NLAB + c) * MAXM + tid] = Mrow;
        float emaval = 0.0f;
        if (act) {
            float rs = 0.0f; int dg = 0;
            for (int j = 0; j < m; ++j) {
                if ((sub >> j) & 1ull) {       // includes j == tid (diag ~ 1.0)
                    float v = Gs[tid][j];
                    if (v > 0.0f) { rs += v; ++dg; }
                }
            }
            float deg = (float)(dg > 0 ? dg : 1);
            float score = 1.0f / (1.0f + expf(-rs / deg));
            emaval = 0.45f + 0.1f * score;     // MOM*0.5 + (1-MOM)*score
        }
        ema[((size_t)l * NLAB + c) * MAXM + tid] = emaval;
    }
}

// ---------------------------------------------------------------------------
// Per (label, pair p in 0..6): recompute G_p, G_{p+1}; masked reduction
// ---------------------------------------------------------------------------
__global__ __launch_bounds__(NTH) void k_pairs(
    const float* __restrict__ feats, const int* __restrict__ members,
    const int* __restrict__ cnt, const unsigned long long* __restrict__ Mbits,
    const float* __restrict__ ema,
    float* accn, float* accd, float* accc)
{
    __shared__ float Xt[128][67];
    __shared__ float G0[64][65];
    __shared__ float G1[64][65];
    __shared__ float rinv[64];
    __shared__ unsigned long long M0s[64], M1s[64];
    __shared__ float es[64];
    __shared__ int g_s[64];
    int c = blockIdx.x, p = blockIdx.y, tid = threadIdx.x;
    int m = cnt[c]; if (m > MAXM) m = MAXM;
    if (m == 0) return;
    if (tid < m) {
        g_s[tid] = members[c * MAXM + tid];
        M0s[tid] = Mbits[((size_t)p * NLAB + c) * MAXM + tid];
        M1s[tid] = Mbits[((size_t)(p + 1) * NLAB + c) * MAXM + tid];
        es[tid]  = ema[((size_t)p * NLAB + c) * MAXM + tid];   // W from shallow layer p
    }
    __syncthreads();
    gram_compute(feats + (size_t)p       * NB * ND, g_s, m, tid, Xt, G0, rinv);
    gram_compute(feats + (size_t)(p + 1) * NB * ND, g_s, m, tid, Xt, G1, rinv);

    float fn = 0.0f, fd = 0.0f, fc = 0.0f;
    for (int idx = tid; idx < (m << 6); idx += NTH) {
        int i = idx >> 6, j = idx & 63;
        if (j >= m) continue;
        bool b0 = (M0s[i] >> j) & 1ull;
        bool b1 = (M1s[i] >> j) & 1ull;
        if (b0 | b1) {
            float a0 = b0 ? G0[i][j] : 0.0f;   // A_tgt
            float a1 = b1 ? G1[i][j] : 0.0f;   // A_deep
            float w = es[i] * es[j];
            float d = a1 - a0;
            fn = fmaf(d * d, w, fn);
            fd += w;
            fc += 1.0f;
        }
    }
    for (int off = 32; off > 0; off >>= 1) {
        fn += __shfl_down(fn, off);
        fd += __shfl_down(fd, off);
        fc += __shfl_down(fc, off);
    }
    if ((tid & 63) == 0) {
        atomicAdd(&accn[p], fn);
        atomicAdd(&accd[p], fd);
        atomicAdd(&accc[p], fc);
    }
}

__global__ void k_final(const float* __restrict__ accn, const float* __restrict__ accd,
                        const float* __restrict__ accc, float* __restrict__ out)
{
    if (threadIdx.x == 0 && blockIdx.x == 0) {
        float s = 0.0f;
        for (int p = 0; p < NL - 1; ++p)
            if (accc[p] > 0.0f) s += accn[p] / fmaxf(accd[p], 1e-8f);
        out[0] = 16.0f * s / 7.0f;    // LAMBDA_ALIGN_K * sum / (L-1)
    }
}

extern "C" void kernel_launch(void* const* d_in, const int* in_sizes, int n_in,
                              void* d_out, int out_size, void* d_ws, size_t ws_size,
                              hipStream_t stream) {
    const float* feats  = (const float*)d_in[0];
    const int*   labels = (const int*)d_in[1];
    // (sample_ids unused by the reference)
    char* w = (char*)d_ws;
    int* members                 = (int*)(w);                    // 128*64*4   = 32768
    int* cnt                     = (int*)(w + 32768);            // 128*4      = 512
    unsigned long long* insub    = (unsigned long long*)(w + 33280);   // 128*8 = 1024
    unsigned long long* Mbits    = (unsigned long long*)(w + 34304);   // 8*128*64*8 = 524288
    float* ema                   = (float*)(w + 558592);         // 8*128*64*4 = 262144
    float* accn                  = (float*)(w + 820736);
    float* accd                  = accn + 7;
    float* accc                  = accn + 14;
    float* out                   = (float*)d_out;

    k_bucket<<<NLAB, NTH, 0, stream>>>(labels, members, cnt, accn, accd, accc);
    k_phase1<<<NLAB, NTH, 0, stream>>>(feats, members, cnt, insub);
    k_decide<<<dim3(NLAB, NL), NTH, 0, stream>>>(feats, members, cnt, insub, Mbits, ema);
    k_pairs<<<dim3(NLAB, NL - 1), NTH, 0, stream>>>(feats, members, cnt, Mbits, ema, accn, accd, accc);
    k_final<<<1, 64, 0, stream>>>(accn, accd, accc, out);
}

// Round 2
// 244.154 us; speedup vs baseline: 1.3325x; 1.3325x over previous
//
#include <hip/hip_runtime.h>
#include <cmath>

#define NB   2048
#define ND   512
#define NL   8
#define NLAB 128
#define MAXM 64
#define TOPK_ 5
#define NTH  256
#define MAXSLOT 9            // ceil(64*65/2 / 256)
#define GSTRIDE (MAXM*MAXM)  // 4096 floats per (label,layer) gram

// ---------------------------------------------------------------------------
// Bucket labels -> ordered member lists (index-ascending, deterministic).
// Also zeroes the pair accumulators (ws is re-poisoned before every call).
// ---------------------------------------------------------------------------
__global__ __launch_bounds__(NTH) void k_bucket(
    const int* __restrict__ labels, int* __restrict__ members,
    int* __restrict__ cnt, float* accn, float* accd, float* accc)
{
    __shared__ int cnts[NTH];
    int c = blockIdx.x, tid = threadIdx.x;
    int my[8]; int n = 0;
    int base_i = tid * 8;
    for (int t = 0; t < 8; ++t) {
        int i = base_i + t;
        if (labels[i] == c) my[n++] = i;
    }
    cnts[tid] = n;
    __syncthreads();
    for (int off = 1; off < NTH; off <<= 1) {
        int v = (tid >= off) ? cnts[tid - off] : 0;
        __syncthreads();
        cnts[tid] += v;
        __syncthreads();
    }
    int excl = cnts[tid] - n;
    if (tid == 0) cnt[c] = cnts[NTH - 1];
    for (int t = 0; t < n; ++t) {
        int slot = excl + t;
        if (slot < MAXM) members[c * MAXM + slot] = my[t];
    }
    if (c == 0 && tid < NL - 1) { accn[tid] = 0.f; accd[tid] = 0.f; accc[tid] = 0.f; }
}

// ---------------------------------------------------------------------------
// Kernel A: raw Gram (un-normalized dot products incl. diag) per (label,layer).
// float4 global loads -> ds_write_b128 staging; ds_read_b128 dot loop.
// Grid (NLAB, NL) = 1024 blocks, 34KB LDS -> 4 blocks/CU, all co-resident.
// ---------------------------------------------------------------------------
__global__ __launch_bounds__(NTH) void k_gram(
    const float* __restrict__ feats, const int* __restrict__ members,
    const int* __restrict__ cnt, float* __restrict__ G)
{
    __shared__ float Xt[MAXM][132];   // 132%4==0 -> aligned float4 rows
    __shared__ int g_s[MAXM];
    int c = blockIdx.x, l = blockIdx.y, tid = threadIdx.x;
    int m = cnt[c]; if (m > MAXM) m = MAXM;
    if (m == 0) return;
    if (tid < m) g_s[tid] = members[c * MAXM + tid];
    __syncthreads();
    const float* X = feats + (size_t)l * NB * ND;

    const int P = m * (m + 1) / 2;    // triangular incl. diag
    float acc0[MAXSLOT], acc1[MAXSLOT];
    short is_[MAXSLOT], js_[MAXSLOT];
    int ns = 0;
    for (int p = tid; p < P; p += NTH) {
        int i = (int)((sqrtf(8.0f * (float)p + 1.0f) - 1.0f) * 0.5f);
        while (((i + 1) * (i + 2)) / 2 <= p) ++i;
        while ((i * (i + 1)) / 2 > p) --i;
        is_[ns] = (short)i;
        js_[ns] = (short)(p - (i * (i + 1)) / 2);
        acc0[ns] = 0.0f; acc1[ns] = 0.0f;
        ++ns;
    }
    for (int kc = 0; kc < ND; kc += 128) {
        if (kc) __syncthreads();      // previous chunk's readers done
        for (int idx = tid; idx < (m << 5); idx += NTH) {
            int i = idx >> 5, k4 = idx & 31;
            float4 v = *(const float4*)(X + ((size_t)g_s[i] << 9) + kc + (k4 << 2));
            *(float4*)&Xt[i][k4 << 2] = v;
        }
        __syncthreads();
        for (int s = 0; s < ns; ++s) {
            int i = is_[s], j = js_[s];
            float a0 = acc0[s], a1 = acc1[s];
            #pragma unroll
            for (int k4 = 0; k4 < 32; ++k4) {
                float4 a = *(const float4*)&Xt[i][k4 << 2];
                float4 b = *(const float4*)&Xt[j][k4 << 2];
                a0 = fmaf(a.x, b.x, a0); a1 = fmaf(a.y, b.y, a1);
                a0 = fmaf(a.z, b.z, a0); a1 = fmaf(a.w, b.w, a1);
            }
            acc0[s] = a0; acc1[s] = a1;
        }
    }
    float* Gc = G + ((size_t)l * NLAB + c) * GSTRIDE;
    for (int s = 0; s < ns; ++s) {
        int i = is_[s], j = js_[s];
        float v = acc0[s] + acc1[s];
        Gc[i * MAXM + j] = v;
        Gc[j * MAXM + i] = v;
    }
}

// ---------------------------------------------------------------------------
// Phase 1: layer-7 full-group knn from stored Gram -> in_sub bitmask
// ---------------------------------------------------------------------------
__global__ __launch_bounds__(NTH) void k_phase1(
    const float* __restrict__ G, const int* __restrict__ cnt,
    unsigned long long* __restrict__ insub)
{
    __shared__ float Gs[64][65];
    __shared__ float rinv[64];
    __shared__ unsigned long long tops_s[64];
    __shared__ unsigned char keep_s[64];
    int c = blockIdx.x, tid = threadIdx.x;
    int m = cnt[c]; if (m > MAXM) m = MAXM;
    if (m == 0) { if (tid == 0) insub[c] = 0ull; return; }
    const float* Gc = G + ((size_t)7 * NLAB + c) * GSTRIDE;
    if (tid < m) rinv[tid] = 1.0f / fmaxf(sqrtf(Gc[tid * MAXM + tid]), 1e-8f);
    __syncthreads();
    for (int idx = tid; idx < (m << 6); idx += NTH) {
        int i = idx >> 6, j = idx & 63;
        if (j < m) {
            float v = Gc[idx] * rinv[i] * rinv[j];
            Gs[i][j] = fminf(fmaxf(v, -1.0f), 1.0f);  // jax f32 clip == +-1.0f
        }
    }
    __syncthreads();

    unsigned long long tops = 0ull; bool keep = false;
    if (tid < m) {
        int cand = 0;
        for (int j = 0; j < m; ++j)
            if (j != tid && Gs[tid][j] > 0.0f) ++cand;
        keep = (cand >= TOPK_);
        if (keep) {
            for (int r = 0; r < TOPK_; ++r) {
                float bv = 0.0f; int bj = -1;
                for (int j = 0; j < m; ++j) {
                    if (j == tid || ((tops >> j) & 1ull)) continue;
                    float v = Gs[tid][j];
                    if (v > 0.0f && v > bv) { bv = v; bj = j; }  // ties -> lowest index
                }
                if (bj >= 0) tops |= (1ull << bj);
            }
        }
        keep_s[tid] = keep ? 1 : 0; tops_s[tid] = tops;
    }
    __syncthreads();
    unsigned long long Mrow = 0ull;
    if (tid < m && keep) {
        for (int j = 0; j < m; ++j) {
            if (j == tid || !keep_s[j]) continue;
            if (((tops >> j) & 1ull) || ((tops_s[j] >> tid) & 1ull)) Mrow |= (1ull << j);
        }
    }
    if (tid < 64) {
        unsigned long long b = __ballot(Mrow != 0ull);
        if (tid == 0) insub[c] = b;
    }
}

// ---------------------------------------------------------------------------
// Per (label, layer): subset-restricted knn from stored Gram -> M bits + ema
// ---------------------------------------------------------------------------
__global__ __launch_bounds__(NTH) void k_decide(
    const float* __restrict__ G, const int* __restrict__ cnt,
    const unsigned long long* __restrict__ insub,
    unsigned long long* __restrict__ Mbits, float* __restrict__ ema)
{
    __shared__ float Gs[64][65];
    __shared__ float rinv[64];
    __shared__ unsigned long long tops_s[64];
    __shared__ unsigned char keep_s[64];
    int c = blockIdx.x, l = blockIdx.y, tid = threadIdx.x;
    int m = cnt[c]; if (m > MAXM) m = MAXM;
    if (m == 0) return;
    unsigned long long sub = insub[c];
    const float* Gc = G + ((size_t)l * NLAB + c) * GSTRIDE;
    if (tid < m) rinv[tid] = 1.0f / fmaxf(sqrtf(Gc[tid * MAXM + tid]), 1e-8f);
    __syncthreads();
    for (int idx = tid; idx < (m << 6); idx += NTH) {
        int i = idx >> 6, j = idx & 63;
        if (j < m) {
            float v = Gc[idx] * rinv[i] * rinv[j];
            Gs[i][j] = fminf(fmaxf(v, -1.0f), 1.0f);
        }
    }
    __syncthreads();

    unsigned long long tops = 0ull; bool keep = false; bool act = false;
    if (tid < m) {
        act = (sub >> tid) & 1ull;
        int cand = 0;
        if (act) {
            for (int j = 0; j < m; ++j)
                if (j != tid && ((sub >> j) & 1ull) && Gs[tid][j] > 0.0f) ++cand;
        }
        keep = act && (cand >= TOPK_);
        if (keep) {
            for (int r = 0; r < TOPK_; ++r) {
                float bv = 0.0f; int bj = -1;
                for (int j = 0; j < m; ++j) {
                    if (j == tid || !((sub >> j) & 1ull) || ((tops >> j) & 1ull)) continue;
                    float v = Gs[tid][j];
                    if (v > 0.0f && v > bv) { bv = v; bj = j; }
                }
                if (bj >= 0) tops |= (1ull << bj);
            }
        }
        keep_s[tid] = keep ? 1 : 0; tops_s[tid] = tops;
    }
    __syncthreads();
    if (tid < m) {
        unsigned long long Mrow = 0ull;
        if (keep) {
            for (int j = 0; j < m; ++j) {
                if (j == tid || !keep_s[j]) continue;
                if (((tops >> j) & 1ull) || ((tops_s[j] >> tid) & 1ull)) Mrow |= (1ull << j);
            }
        }
        Mbits[((size_t)l * NLAB + c) * MAXM + tid] = Mrow;
        float emaval = 0.0f;
        if (act) {
            float rs = 0.0f; int dg = 0;
            for (int j = 0; j < m; ++j) {
                if ((sub >> j) & 1ull) {        // includes j == tid (diag ~ 1.0)
                    float v = Gs[tid][j];
                    if (v > 0.0f) { rs += v; ++dg; }
                }
            }
            float deg = (float)(dg > 0 ? dg : 1);
            float score = 1.0f / (1.0f + expf(-rs / deg));
            emaval = 0.45f + 0.1f * score;      // MOM*0.5 + (1-MOM)*score
        }
        ema[((size_t)l * NLAB + c) * MAXM + tid] = emaval;
    }
}

// ---------------------------------------------------------------------------
// Per (label, pair p): read stored Grams, normalize on the fly, masked reduce
// ---------------------------------------------------------------------------
__global__ __launch_bounds__(NTH) void k_pairs(
    const float* __restrict__ G, const int* __restrict__ cnt,
    const unsigned long long* __restrict__ Mbits, const float* __restrict__ ema,
    float* accn, float* accd, float* accc)
{
    __shared__ float r0[64], r1[64];
    __shared__ unsigned long long M0s[64], M1s[64];
    __shared__ float es[64];
    int c = blockIdx.x, p = blockIdx.y, tid = threadIdx.x;
    int m = cnt[c]; if (m > MAXM) m = MAXM;
    if (m == 0) return;
    const float* G0 = G + ((size_t)p       * NLAB + c) * GSTRIDE;
    const float* G1 = G + ((size_t)(p + 1) * NLAB + c) * GSTRIDE;
    if (tid < m) {
        M0s[tid] = Mbits[((size_t)p * NLAB + c) * MAXM + tid];
        M1s[tid] = Mbits[((size_t)(p + 1) * NLAB + c) * MAXM + tid];
        es[tid]  = ema[((size_t)p * NLAB + c) * MAXM + tid];   // W from shallow layer p
        r0[tid]  = 1.0f / fmaxf(sqrtf(G0[tid * MAXM + tid]), 1e-8f);
        r1[tid]  = 1.0f / fmaxf(sqrtf(G1[tid * MAXM + tid]), 1e-8f);
    }
    __syncthreads();
    float fn = 0.0f, fd = 0.0f, fc = 0.0f;
    for (int idx = tid; idx < (m << 6); idx += NTH) {
        int i = idx >> 6, j = idx & 63;
        if (j >= m) continue;
        bool b0 = (M0s[i] >> j) & 1ull;
        bool b1 = (M1s[i] >> j) & 1ull;
        if (b0 | b1) {
            float v0 = b0 ? fminf(fmaxf(G0[idx] * r0[i] * r0[j], -1.0f), 1.0f) : 0.0f;
            float v1 = b1 ? fminf(fmaxf(G1[idx] * r1[i] * r1[j], -1.0f), 1.0f) : 0.0f;
            float w = es[i] * es[j];
            float d = v1 - v0;
            fn = fmaf(d * d, w, fn);
            fd += w;
            fc += 1.0f;
        }
    }
    for (int off = 32; off > 0; off >>= 1) {
        fn += __shfl_down(fn, off);
        fd += __shfl_down(fd, off);
        fc += __shfl_down(fc, off);
    }
    if ((tid & 63) == 0) {
        atomicAdd(&accn[p], fn);
        atomicAdd(&accd[p], fd);
        atomicAdd(&accc[p], fc);
    }
}

__global__ void k_final(const float* __restrict__ accn, const float* __restrict__ accd,
                        const float* __restrict__ accc, float* __restrict__ out)
{
    if (threadIdx.x == 0 && blockIdx.x == 0) {
        float s = 0.0f;
        for (int p = 0; p < NL - 1; ++p)
            if (accc[p] > 0.0f) s += accn[p] / fmaxf(accd[p], 1e-8f);
        out[0] = 16.0f * s / 7.0f;    // LAMBDA_ALIGN_K * sum / (L-1)
    }
}

extern "C" void kernel_launch(void* const* d_in, const int* in_sizes, int n_in,
                              void* d_out, int out_size, void* d_ws, size_t ws_size,
                              hipStream_t stream) {
    const float* feats  = (const float*)d_in[0];
    const int*   labels = (const int*)d_in[1];
    // (sample_ids unused by the reference)
    char* w = (char*)d_ws;
    int* members              = (int*)(w);                            // 32768
    int* cnt                  = (int*)(w + 32768);                    // 512
    unsigned long long* insub = (unsigned long long*)(w + 33280);     // 1024
    unsigned long long* Mbits = (unsigned long long*)(w + 34304);     // 524288
    float* ema                = (float*)(w + 558592);                 // 262144
    float* accn               = (float*)(w + 820736);                 // 84
    float* accd               = accn + 7;
    float* accc               = accn + 14;
    float* G                  = (float*)(w + 821248);                 // 8*128*4096*4 = 16.8MB
    float* out                = (float*)d_out;

    k_bucket<<<NLAB, NTH, 0, stream>>>(labels, members, cnt, accn, accd, accc);
    k_gram  <<<dim3(NLAB, NL), NTH, 0, stream>>>(feats, members, cnt, G);
    k_phase1<<<NLAB, NTH, 0, stream>>>(G, cnt, insub);
    k_decide<<<dim3(NLAB, NL), NTH, 0, stream>>>(G, cnt, insub, Mbits, ema);
    k_pairs <<<dim3(NLAB, NL - 1), NTH, 0, stream>>>(G, cnt, Mbits, ema, accn, accd, accc);
    k_final <<<1, 64, 0, stream>>>(accn, accd, accc, out);
}

// Round 3
// 147.042 us; speedup vs baseline: 2.2125x; 1.6604x over previous
//
#include <hip/hip_runtime.h>
#include <cmath>

#define NB   2048
#define ND   512
#define NL   8
#define NLAB 128
#define MAXM 64
#define TOPK_ 5
#define NTH  256
#define MAXSLOT 9            // ceil(64*65/2 / 256)
#define GSTRIDE (MAXM*MAXM)  // 4096 floats per (label,layer) gram

// ---------------------------------------------------------------------------
// Bucket labels -> ordered member lists (index-ascending, deterministic).
// ---------------------------------------------------------------------------
__global__ __launch_bounds__(NTH) void k_bucket(
    const int* __restrict__ labels, int* __restrict__ members,
    int* __restrict__ cnt)
{
    __shared__ int cnts[NTH];
    int c = blockIdx.x, tid = threadIdx.x;
    int my[8]; int n = 0;
    int base_i = tid * 8;
    for (int t = 0; t < 8; ++t) {
        int i = base_i + t;
        if (labels[i] == c) my[n++] = i;
    }
    cnts[tid] = n;
    __syncthreads();
    for (int off = 1; off < NTH; off <<= 1) {
        int v = (tid >= off) ? cnts[tid - off] : 0;
        __syncthreads();
        cnts[tid] += v;
        __syncthreads();
    }
    int excl = cnts[tid] - n;
    if (tid == 0) cnt[c] = cnts[NTH - 1];
    for (int t = 0; t < n; ++t) {
        int slot = excl + t;
        if (slot < MAXM) members[c * MAXM + slot] = my[t];
    }
}

// ---------------------------------------------------------------------------
// Raw Gram (un-normalized dots incl. diag) per (label,layer).
// float4 global loads -> ds_write_b128 staging; ds_read_b128 dot loop.
// ---------------------------------------------------------------------------
__global__ __launch_bounds__(NTH) void k_gram(
    const float* __restrict__ feats, const int* __restrict__ members,
    const int* __restrict__ cnt, float* __restrict__ G)
{
    __shared__ float Xt[MAXM][132];   // 132%4==0 -> aligned float4 rows
    __shared__ int g_s[MAXM];
    int c = blockIdx.x, l = blockIdx.y, tid = threadIdx.x;
    int m = cnt[c]; if (m > MAXM) m = MAXM;
    if (m == 0) return;
    if (tid < m) g_s[tid] = members[c * MAXM + tid];
    __syncthreads();
    const float* X = feats + (size_t)l * NB * ND;

    const int P = m * (m + 1) / 2;    // triangular incl. diag
    float acc0[MAXSLOT], acc1[MAXSLOT];
    short is_[MAXSLOT], js_[MAXSLOT];
    int ns = 0;
    for (int p = tid; p < P; p += NTH) {
        int i = (int)((sqrtf(8.0f * (float)p + 1.0f) - 1.0f) * 0.5f);
        while (((i + 1) * (i + 2)) / 2 <= p) ++i;
        while ((i * (i + 1)) / 2 > p) --i;
        is_[ns] = (short)i;
        js_[ns] = (short)(p - (i * (i + 1)) / 2);
        acc0[ns] = 0.0f; acc1[ns] = 0.0f;
        ++ns;
    }
    for (int kc = 0; kc < ND; kc += 128) {
        if (kc) __syncthreads();      // previous chunk's readers done
        for (int idx = tid; idx < (m << 5); idx += NTH) {
            int i = idx >> 5, k4 = idx & 31;
            float4 v = *(const float4*)(X + ((size_t)g_s[i] << 9) + kc + (k4 << 2));
            *(float4*)&Xt[i][k4 << 2] = v;
        }
        __syncthreads();
        for (int s = 0; s < ns; ++s) {
            int i = is_[s], j = js_[s];
            float a0 = acc0[s], a1 = acc1[s];
            #pragma unroll
            for (int k4 = 0; k4 < 32; ++k4) {
                float4 a = *(const float4*)&Xt[i][k4 << 2];
                float4 b = *(const float4*)&Xt[j][k4 << 2];
                a0 = fmaf(a.x, b.x, a0); a1 = fmaf(a.y, b.y, a1);
                a0 = fmaf(a.z, b.z, a0); a1 = fmaf(a.w, b.w, a1);
            }
            acc0[s] = a0; acc1[s] = a1;
        }
    }
    float* Gc = G + ((size_t)l * NLAB + c) * GSTRIDE;
    for (int s = 0; s < ns; ++s) {
        int i = is_[s], j = js_[s];
        float v = acc0[s] + acc1[s];
        Gc[i * MAXM + j] = v;
        Gc[j * MAXM + i] = v;
    }
}

// ---------------------------------------------------------------------------
// Phase 1: layer-7 full-group knn from stored Gram -> in_sub bitmask
// ---------------------------------------------------------------------------
__global__ __launch_bounds__(NTH) void k_phase1(
    const float* __restrict__ G, const int* __restrict__ cnt,
    unsigned long long* __restrict__ insub)
{
    __shared__ float Gs[64][65];
    __shared__ float rinv[64];
    __shared__ unsigned long long tops_s[64];
    __shared__ unsigned char keep_s[64];
    int c = blockIdx.x, tid = threadIdx.x;
    int m = cnt[c]; if (m > MAXM) m = MAXM;
    if (m == 0) { if (tid == 0) insub[c] = 0ull; return; }
    const float* Gc = G + ((size_t)7 * NLAB + c) * GSTRIDE;
    if (tid < m) rinv[tid] = 1.0f / fmaxf(sqrtf(Gc[tid * MAXM + tid]), 1e-8f);
    __syncthreads();
    for (int idx = tid; idx < (m << 6); idx += NTH) {
        int i = idx >> 6, j = idx & 63;
        if (j < m) {
            float v = Gc[idx] * rinv[i] * rinv[j];
            Gs[i][j] = fminf(fmaxf(v, -1.0f), 1.0f);  // jax f32 clip == +-1.0f
        }
    }
    __syncthreads();

    unsigned long long tops = 0ull; bool keep = false;
    if (tid < m) {
        int cand = 0;
        for (int j = 0; j < m; ++j)
            if (j != tid && Gs[tid][j] > 0.0f) ++cand;
        keep = (cand >= TOPK_);
        if (keep) {
            for (int r = 0; r < TOPK_; ++r) {
                float bv = 0.0f; int bj = -1;
                for (int j = 0; j < m; ++j) {
                    if (j == tid || ((tops >> j) & 1ull)) continue;
                    float v = Gs[tid][j];
                    if (v > 0.0f && v > bv) { bv = v; bj = j; }  // ties -> lowest index
                }
                if (bj >= 0) tops |= (1ull << bj);
            }
        }
        keep_s[tid] = keep ? 1 : 0; tops_s[tid] = tops;
    }
    __syncthreads();
    unsigned long long Mrow = 0ull;
    if (tid < m && keep) {
        for (int j = 0; j < m; ++j) {
            if (j == tid || !keep_s[j]) continue;
            if (((tops >> j) & 1ull) || ((tops_s[j] >> tid) & 1ull)) Mrow |= (1ull << j);
        }
    }
    if (tid < 64) {
        unsigned long long b = __ballot(Mrow != 0ull);
        if (tid == 0) insub[c] = b;
    }
}

// ---------------------------------------------------------------------------
// Per (label, layer): subset-restricted knn from stored Gram -> M bits + ema
// ---------------------------------------------------------------------------
__global__ __launch_bounds__(NTH) void k_decide(
    const float* __restrict__ G, const int* __restrict__ cnt,
    const unsigned long long* __restrict__ insub,
    unsigned long long* __restrict__ Mbits, float* __restrict__ ema)
{
    __shared__ float Gs[64][65];
    __shared__ float rinv[64];
    __shared__ unsigned long long tops_s[64];
    __shared__ unsigned char keep_s[64];
    int c = blockIdx.x, l = blockIdx.y, tid = threadIdx.x;
    int m = cnt[c]; if (m > MAXM) m = MAXM;
    if (m == 0) return;
    unsigned long long sub = insub[c];
    const float* Gc = G + ((size_t)l * NLAB + c) * GSTRIDE;
    if (tid < m) rinv[tid] = 1.0f / fmaxf(sqrtf(Gc[tid * MAXM + tid]), 1e-8f);
    __syncthreads();
    for (int idx = tid; idx < (m << 6); idx += NTH) {
        int i = idx >> 6, j = idx & 63;
        if (j < m) {
            float v = Gc[idx] * rinv[i] * rinv[j];
            Gs[i][j] = fminf(fmaxf(v, -1.0f), 1.0f);
        }
    }
    __syncthreads();

    unsigned long long tops = 0ull; bool keep = false; bool act = false;
    if (tid < m) {
        act = (sub >> tid) & 1ull;
        int cand = 0;
        if (act) {
            for (int j = 0; j < m; ++j)
                if (j != tid && ((sub >> j) & 1ull) && Gs[tid][j] > 0.0f) ++cand;
        }
        keep = act && (cand >= TOPK_);
        if (keep) {
            for (int r = 0; r < TOPK_; ++r) {
                float bv = 0.0f; int bj = -1;
                for (int j = 0; j < m; ++j) {
                    if (j == tid || !((sub >> j) & 1ull) || ((tops >> j) & 1ull)) continue;
                    float v = Gs[tid][j];
                    if (v > 0.0f && v > bv) { bv = v; bj = j; }
                }
                if (bj >= 0) tops |= (1ull << bj);
            }
        }
        keep_s[tid] = keep ? 1 : 0; tops_s[tid] = tops;
    }
    __syncthreads();
    if (tid < m) {
        unsigned long long Mrow = 0ull;
        if (keep) {
            for (int j = 0; j < m; ++j) {
                if (j == tid || !keep_s[j]) continue;
                if (((tops >> j) & 1ull) || ((tops_s[j] >> tid) & 1ull)) Mrow |= (1ull << j);
            }
        }
        Mbits[((size_t)l * NLAB + c) * MAXM + tid] = Mrow;
        float emaval = 0.0f;
        if (act) {
            float rs = 0.0f; int dg = 0;
            for (int j = 0; j < m; ++j) {
                if ((sub >> j) & 1ull) {        // includes j == tid (diag ~ 1.0)
                    float v = Gs[tid][j];
                    if (v > 0.0f) { rs += v; ++dg; }
                }
            }
            float deg = (float)(dg > 0 ? dg : 1);
            float score = 1.0f / (1.0f + expf(-rs / deg));
            emaval = 0.45f + 0.1f * score;      // MOM*0.5 + (1-MOM)*score
        }
        ema[((size_t)l * NLAB + c) * MAXM + tid] = emaval;
    }
}

// ---------------------------------------------------------------------------
// Per (label, pair p): masked reduce -> per-block PRIVATE partial slot.
// NO atomics (round-2 profile: 10752 same-line atomicAdds = 109us stall).
// ---------------------------------------------------------------------------
__global__ __launch_bounds__(NTH) void k_pairs(
    const float* __restrict__ G, const int* __restrict__ cnt,
    const unsigned long long* __restrict__ Mbits, const float* __restrict__ ema,
    float* __restrict__ partial)   // [NL-1][NLAB][4]
{
    __shared__ float r0[64], r1[64];
    __shared__ unsigned long long M0s[64], M1s[64];
    __shared__ float es[64];
    __shared__ float red[12];      // 4 waves x 3
    int c = blockIdx.x, p = blockIdx.y, tid = threadIdx.x;
    int m = cnt[c]; if (m > MAXM) m = MAXM;
    const float* G0 = G + ((size_t)p       * NLAB + c) * GSTRIDE;
    const float* G1 = G + ((size_t)(p + 1) * NLAB + c) * GSTRIDE;
    if (tid < m) {
        M0s[tid] = Mbits[((size_t)p * NLAB + c) * MAXM + tid];
        M1s[tid] = Mbits[((size_t)(p + 1) * NLAB + c) * MAXM + tid];
        es[tid]  = ema[((size_t)p * NLAB + c) * MAXM + tid];   // W from shallow layer p
        r0[tid]  = 1.0f / fmaxf(sqrtf(G0[tid * MAXM + tid]), 1e-8f);
        r1[tid]  = 1.0f / fmaxf(sqrtf(G1[tid * MAXM + tid]), 1e-8f);
    }
    __syncthreads();
    float fn = 0.0f, fd = 0.0f, fc = 0.0f;
    for (int idx = tid; idx < (m << 6); idx += NTH) {
        int i = idx >> 6, j = idx & 63;
        if (j >= m) continue;
        bool b0 = (M0s[i] >> j) & 1ull;
        bool b1 = (M1s[i] >> j) & 1ull;
        if (b0 | b1) {
            float v0 = b0 ? fminf(fmaxf(G0[idx] * r0[i] * r0[j], -1.0f), 1.0f) : 0.0f;
            float v1 = b1 ? fminf(fmaxf(G1[idx] * r1[i] * r1[j], -1.0f), 1.0f) : 0.0f;
            float w = es[i] * es[j];
            float d = v1 - v0;
            fn = fmaf(d * d, w, fn);
            fd += w;
            fc += 1.0f;
        }
    }
    for (int off = 32; off > 0; off >>= 1) {
        fn += __shfl_down(fn, off);
        fd += __shfl_down(fd, off);
        fc += __shfl_down(fc, off);
    }
    int w = tid >> 6;
    if ((tid & 63) == 0) { red[w * 3] = fn; red[w * 3 + 1] = fd; red[w * 3 + 2] = fc; }
    __syncthreads();
    if (tid == 0) {
        float* dst = partial + ((size_t)p * NLAB + c) * 4;
        dst[0] = red[0] + red[3] + red[6] + red[9];
        dst[1] = red[1] + red[4] + red[7] + red[10];
        dst[2] = red[2] + red[5] + red[8] + red[11];
    }
}

// Single-wave final reduction over 896 private slots (~10.5 KB, L2-hit).
__global__ void k_final(const float* __restrict__ partial, float* __restrict__ out)
{
    int tid = threadIdx.x;
    float total = 0.0f;
    for (int p = 0; p < NL - 1; ++p) {
        float n = 0.0f, d = 0.0f, cc = 0.0f;
        for (int c = tid; c < NLAB; c += 64) {
            const float* src = partial + ((size_t)p * NLAB + c) * 4;
            n += src[0]; d += src[1]; cc += src[2];
        }
        for (int off = 32; off > 0; off >>= 1) {
            n += __shfl_down(n, off);
            d += __shfl_down(d, off);
            cc += __shfl_down(cc, off);
        }
        if (tid == 0 && cc > 0.0f) total += n / fmaxf(d, 1e-8f);
    }
    if (tid == 0) out[0] = 16.0f * total / 7.0f;   // LAMBDA_ALIGN_K * sum / (L-1)
}

extern "C" void kernel_launch(void* const* d_in, const int* in_sizes, int n_in,
                              void* d_out, int out_size, void* d_ws, size_t ws_size,
                              hipStream_t stream) {
    const float* feats  = (const float*)d_in[0];
    const int*   labels = (const int*)d_in[1];
    // (sample_ids unused by the reference)
    char* w = (char*)d_ws;
    int* members              = (int*)(w);                            // 32768
    int* cnt                  = (int*)(w + 32768);                    // 512
    unsigned long long* insub = (unsigned long long*)(w + 33280);     // 1024
    unsigned long long* Mbits = (unsigned long long*)(w + 34304);     // 524288
    float* ema                = (float*)(w + 558592);                 // 262144
    float* G                  = (float*)(w + 821248);                 // 16.8 MB
    float* partial            = (float*)(w + 821248 + (size_t)NL * NLAB * GSTRIDE * 4); // 14336
    float* out                = (float*)d_out;

    k_bucket<<<NLAB, NTH, 0, stream>>>(labels, members, cnt);
    k_gram  <<<dim3(NLAB, NL), NTH, 0, stream>>>(feats, members, cnt, G);
    k_phase1<<<NLAB, NTH, 0, stream>>>(G, cnt, insub);
    k_decide<<<dim3(NLAB, NL), NTH, 0, stream>>>(G, cnt, insub, Mbits, ema);
    k_pairs <<<dim3(NLAB, NL - 1), NTH, 0, stream>>>(G, cnt, Mbits, ema, partial);
    k_final <<<1, 64, 0, stream>>>(partial, out);
}